// Round 9
// baseline (249.572 us; speedup 1.0000x reference)
//
#include <hip/hip_runtime.h>

typedef __bf16 bhalf;
typedef __bf16 bhalf8 __attribute__((ext_vector_type(8)));
typedef __bf16 bhalf4 __attribute__((ext_vector_type(4)));
typedef __bf16 bhalf2 __attribute__((ext_vector_type(2)));
typedef float f32x4 __attribute__((ext_vector_type(4)));

typedef __attribute__((address_space(1))) const void* gas_p;
typedef __attribute__((address_space(3))) void* las_p;

#define T_SEQ 2048
#define HIDN  2048
#define NQH   32
#define NKVH  8
#define DH    64
#define NQKV  3072

// ---------------- fused prep: cast + weight transposes + RoPE table ----------------
__global__ __launch_bounds__(256) void prep_k(const float* __restrict__ hidden,
                                              const float* __restrict__ w_qkv,
                                              const float* __restrict__ w_out,
                                              const int* __restrict__ pos,
                                              bhalf* __restrict__ hid_bf,
                                              bhalf* __restrict__ wqkvT,
                                              bhalf* __restrict__ woutT,
                                              float* __restrict__ rope) {
  __shared__ float tile[64][65];
  int bid = blockIdx.x;
  int tx = threadIdx.x;
  if (bid < 4096) {
    int i = (bid * 256 + tx) * 4;
    float4 v = *(const float4*)(hidden + i);
    bhalf4 o;
    o[0] = (bhalf)v.x; o[1] = (bhalf)v.y; o[2] = (bhalf)v.z; o[3] = (bhalf)v.w;
    *(bhalf4*)(hid_bf + i) = o;
    return;
  }
  if (bid >= 6656) {
    int gid = (bid - 6656) * 256 + tx;   // 32768 = 2048 t x 16 j
    int t = gid >> 4, j = gid & 15;
    float p = (float)pos[t];
    float f0 = exp2f((float)j * -0.6228615177913804f);  // theta^(-j/32)
    float a0 = p * f0, a1 = p * f0 * 0.001f;            // theta^(-16/32) = 1e-3
    float4 cs = {cosf(a0), sinf(a0), cosf(a1), sinf(a1)};
    *(float4*)(rope + (size_t)gid * 4) = cs;
    return;
  }
  const float* in;
  bhalf* out;
  int R, C, bx, by;
  if (bid < 5632) {
    int b2 = bid - 4096;
    in = w_qkv; out = wqkvT; R = HIDN; C = NQKV;
    bx = (b2 % 48) * 64; by = (b2 / 48) * 64;
  } else {
    int b2 = bid - 5632;
    in = w_out; out = woutT; R = HIDN; C = HIDN;
    bx = (b2 % 32) * 64; by = (b2 / 32) * 64;
  }
#pragma unroll
  for (int p = 0; p < 4; ++p) {
    int row = p * 16 + (tx >> 4);
    int col = (tx & 15) * 4;
    float4 v = *(const float4*)(in + (size_t)(by + row) * C + bx + col);
    tile[row][col] = v.x; tile[row][col + 1] = v.y;
    tile[row][col + 2] = v.z; tile[row][col + 3] = v.w;
  }
  __syncthreads();
#pragma unroll
  for (int p = 0; p < 8; ++p) {
    int c = p * 8 + (tx >> 5);
    int rp = tx & 31;
    bhalf2 o2;
    o2[0] = (bhalf)tile[2 * rp][c];
    o2[1] = (bhalf)tile[2 * rp + 1][c];
    *(bhalf2*)(out + (size_t)(bx + c) * R + by + 2 * rp) = o2;
  }
}

#define MFMA_BF16 __builtin_amdgcn_mfma_f32_16x16x32_bf16

// ---- 128x128 GEMM core, double-buffered, compile-time buffer bases ----
#define GEMM_STAGE(Aps, Bps, k0)                                               \
  _Pragma("unroll")                                                            \
  for (int c = 0; c < 4; ++c) {                                                \
    __builtin_amdgcn_global_load_lds(                                          \
        (gas_p)(asrc_ + (size_t)(c * 32) * 2048 + (k0)),                       \
        (las_p)(Aps + woff_ + c * 2048), 16, 0, 0);                            \
    __builtin_amdgcn_global_load_lds(                                          \
        (gas_p)(bsrc_ + (size_t)(c * 32) * 2048 + (k0)),                       \
        (las_p)(Bps + woff_ + c * 2048), 16, 0, 0);                            \
  }

#define GEMM_KS(Aps, Bps, ks)                                                  \
  {                                                                            \
    const int co_ = (((ks) * 4 + q4) ^ swz_) * 8;                              \
    bhalf8 af0 = *(const bhalf8*)&Aps[(wm_ +  0 + m16) * 64 + co_];            \
    bhalf8 af1 = *(const bhalf8*)&Aps[(wm_ + 16 + m16) * 64 + co_];            \
    bhalf8 af2 = *(const bhalf8*)&Aps[(wm_ + 32 + m16) * 64 + co_];            \
    bhalf8 af3 = *(const bhalf8*)&Aps[(wm_ + 48 + m16) * 64 + co_];            \
    bhalf8 bf0 = *(const bhalf8*)&Bps[(wn_ +  0 + m16) * 64 + co_];            \
    bhalf8 bf1 = *(const bhalf8*)&Bps[(wn_ + 16 + m16) * 64 + co_];            \
    bhalf8 bf2 = *(const bhalf8*)&Bps[(wn_ + 32 + m16) * 64 + co_];            \
    bhalf8 bf3 = *(const bhalf8*)&Bps[(wn_ + 48 + m16) * 64 + co_];            \
    acc[0][0] = MFMA_BF16(af0, bf0, acc[0][0], 0, 0, 0);                       \
    acc[0][1] = MFMA_BF16(af0, bf1, acc[0][1], 0, 0, 0);                       \
    acc[0][2] = MFMA_BF16(af0, bf2, acc[0][2], 0, 0, 0);                       \
    acc[0][3] = MFMA_BF16(af0, bf3, acc[0][3], 0, 0, 0);                       \
    acc[1][0] = MFMA_BF16(af1, bf0, acc[1][0], 0, 0, 0);                       \
    acc[1][1] = MFMA_BF16(af1, bf1, acc[1][1], 0, 0, 0);                       \
    acc[1][2] = MFMA_BF16(af1, bf2, acc[1][2], 0, 0, 0);                       \
    acc[1][3] = MFMA_BF16(af1, bf3, acc[1][3], 0, 0, 0);                       \
    acc[2][0] = MFMA_BF16(af2, bf0, acc[2][0], 0, 0, 0);                       \
    acc[2][1] = MFMA_BF16(af2, bf1, acc[2][1], 0, 0, 0);                       \
    acc[2][2] = MFMA_BF16(af2, bf2, acc[2][2], 0, 0, 0);                       \
    acc[2][3] = MFMA_BF16(af2, bf3, acc[2][3], 0, 0, 0);                       \
    acc[3][0] = MFMA_BF16(af3, bf0, acc[3][0], 0, 0, 0);                       \
    acc[3][1] = MFMA_BF16(af3, bf1, acc[3][1], 0, 0, 0);                       \
    acc[3][2] = MFMA_BF16(af3, bf2, acc[3][2], 0, 0, 0);                       \
    acc[3][3] = MFMA_BF16(af3, bf3, acc[3][3], 0, 0, 0);                       \
  }

#define GEMM_CORE_128DB(Aptr, Bptr)                                            \
  {                                                                            \
    const int srow_ = tid >> 3;                                                \
    const int scol_ = ((tid & 7) ^ (srow_ & 7)) * 8;                           \
    const bhalf* asrc_ = (Aptr) + (size_t)(bm + srow_) * 2048 + scol_;         \
    const bhalf* bsrc_ = (Bptr) + (size_t)(bn + srow_) * 2048 + scol_;         \
    const int woff_ = wv * 512;                                                \
    const int swz_ = m16 & 7;                                                  \
    const int wm_ = (wv >> 1) * 64, wn_ = (wv & 1) * 64;                       \
    GEMM_STAGE(As0, Bs0, 0)                                                    \
    for (int k0 = 0; k0 < 2048; k0 += 128) {                                   \
      __syncthreads(); /* buf0 landed; prior buf0 reads done */                \
      GEMM_STAGE(As1, Bs1, k0 + 64)  /* k0+64 <= 1984 always valid */          \
      GEMM_KS(As0, Bs0, 0)                                                     \
      GEMM_KS(As0, Bs0, 1)                                                     \
      __syncthreads(); /* buf1 landed; prior buf1 reads done */                \
      if (k0 + 128 < 2048) GEMM_STAGE(As0, Bs0, k0 + 128)                      \
      GEMM_KS(As1, Bs1, 0)                                                     \
      GEMM_KS(As1, Bs1, 1)                                                     \
    }                                                                          \
  }

// ---------------- GEMM1 + fused RMSNorm + RoPE(table) + split + cast + V-transpose --------
__global__ __launch_bounds__(256, 1) void gemm1_fused_k(const bhalf* __restrict__ A,
                                                        const bhalf* __restrict__ Bt,
                                                        const float* __restrict__ rope,
                                                        const float* __restrict__ qw,
                                                        const float* __restrict__ kw,
                                                        bhalf* __restrict__ qo,
                                                        bhalf* __restrict__ ko,
                                                        bhalf* __restrict__ vt) {
  __shared__ __align__(16) bhalf As0[8192], Bs0[8192], As1[8192], Bs1[8192];
  int tid = threadIdx.x, lane = tid & 63, wv = tid >> 6;
  int m16 = lane & 15, q4 = lane >> 4;
  int orig = blockIdx.x;                      // 384 blocks
  int wgid = (orig & 7) * 48 + (orig >> 3);   // bijective XCD swizzle (384 = 8*48)
  int bx = wgid % 24, by = wgid / 24;
  int bm = by * 128, bn = bx * 128;
  f32x4 zero4 = {0.f, 0.f, 0.f, 0.f};
  f32x4 acc[4][4];
#pragma unroll
  for (int mi = 0; mi < 4; ++mi)
#pragma unroll
    for (int ni = 0; ni < 4; ++ni) acc[mi][ni] = zero4;

  GEMM_CORE_128DB(A, Bt)

  int r0 = bm + (wv >> 1) * 64;
  int hh = (bn >> 6) + (wv & 1);              // head handled by this wave
  if (hh < 40) {
    float wd[4];
    const float* wptr = (hh < 32) ? qw : kw;
    float wscale = (hh < 32) ? 0.18033688011112042f : 1.0f;  // 0.125*log2(e) for Q
#pragma unroll
    for (int ni = 0; ni < 4; ++ni) wd[ni] = wptr[ni * 16 + m16] * wscale;
#pragma unroll
    for (int mi = 0; mi < 4; ++mi)
#pragma unroll
      for (int r = 0; r < 4; ++r) {
        int trow = r0 + mi * 16 + q4 * 4 + r;
        float x0 = acc[mi][0][r], x1 = acc[mi][1][r], x2 = acc[mi][2][r], x3 = acc[mi][3][r];
        float ss = x0 * x0 + x1 * x1 + x2 * x2 + x3 * x3;
        ss += __shfl_xor(ss, 1);
        ss += __shfl_xor(ss, 2);
        ss += __shfl_xor(ss, 4);
        ss += __shfl_xor(ss, 8);
        float sc = rsqrtf(ss * (1.0f / 64.0f) + 1e-5f);
        float y0 = x0 * sc * wd[0], y1 = x1 * sc * wd[1];
        float y2 = x2 * sc * wd[2], y3 = x3 * sc * wd[3];
        float4 cs = *(const float4*)(rope + ((size_t)trow * 16 + m16) * 4);
        float o0 = y0 * cs.x - y2 * cs.y, o2 = y2 * cs.x + y0 * cs.y;
        float o1 = y1 * cs.z - y3 * cs.w, o3 = y3 * cs.z + y1 * cs.w;
        bhalf* dst = (hh < 32) ? (qo + (size_t)trow * 2048 + hh * 64 + m16)
                               : (ko + (size_t)trow * 512 + (hh - 32) * 64 + m16);
        dst[0] = (bhalf)o0; dst[16] = (bhalf)o1; dst[32] = (bhalf)o2; dst[48] = (bhalf)o3;
      }
  } else {
#pragma unroll
    for (int mi = 0; mi < 4; ++mi)
#pragma unroll
      for (int ni = 0; ni < 4; ++ni) {
        int trow0 = r0 + mi * 16 + q4 * 4;
        int d = (hh - 40) * 64 + ni * 16 + m16;
        bhalf4 pk;
        pk[0] = (bhalf)acc[mi][ni][0]; pk[1] = (bhalf)acc[mi][ni][1];
        pk[2] = (bhalf)acc[mi][ni][2]; pk[3] = (bhalf)acc[mi][ni][3];
        *(bhalf4*)(vt + (size_t)d * 2048 + trow0) = pk;
      }
  }
}

// ---------------- GEMM2: plain fp32-out epilogue ----------------
__global__ __launch_bounds__(256, 1) void gemm2_k(const bhalf* __restrict__ A,
                                                  const bhalf* __restrict__ Bt,
                                                  float* __restrict__ C) {
  __shared__ __align__(16) bhalf As0[8192], Bs0[8192], As1[8192], Bs1[8192];
  int tid = threadIdx.x, lane = tid & 63, wv = tid >> 6;
  int m16 = lane & 15, q4 = lane >> 4;
  int orig = blockIdx.x;                      // 256 blocks
  int wgid = (orig & 7) * 32 + (orig >> 3);   // bijective XCD swizzle (256 = 8*32)
  int bx = wgid & 15, by = wgid >> 4;
  int bm = by * 128, bn = bx * 128;
  f32x4 zero4 = {0.f, 0.f, 0.f, 0.f};
  f32x4 acc[4][4];
#pragma unroll
  for (int mi = 0; mi < 4; ++mi)
#pragma unroll
    for (int ni = 0; ni < 4; ++ni) acc[mi][ni] = zero4;

  GEMM_CORE_128DB(A, Bt)

  int r0 = bm + (wv >> 1) * 64;
  int c0 = bn + (wv & 1) * 64;
#pragma unroll
  for (int mi = 0; mi < 4; ++mi)
#pragma unroll
    for (int r = 0; r < 4; ++r) {
      size_t base = (size_t)(r0 + mi * 16 + q4 * 4 + r) * 2048 + c0 + m16;
      C[base] = acc[mi][0][r]; C[base + 16] = acc[mi][1][r];
      C[base + 32] = acc[mi][2][r]; C[base + 48] = acc[mi][3][r];
    }
}

// ---------------- flash attention (causal GQA), fixed-max softmax ----------------
// R7 grid (NQH, 32), 1024 blocks, 4/CU. CHANGE: V is no longer LDS-staged —
// each wave loads its private V^T fragments directly from global (L2-resident,
// identical addresses to the old staging path, so fragment layout is unchanged).
// Removes 8/18 LDS reads per wave-chunk, halves the gload_lds drain at each
// barrier, and prefetches V under QK^T+softmax (T14 issue-early/consume-late).
// LDS: Kb 16KB + Pb 8KB = 24KB.
__global__ __launch_bounds__(256) void attn_k(const bhalf* __restrict__ q,
                                              const bhalf* __restrict__ k,
                                              const bhalf* __restrict__ vt,
                                              bhalf* __restrict__ o) {
  __shared__ __align__(16) bhalf Kb[2][4096];
  __shared__ __align__(16) bhalf Pb[4][16][64];
  int tid = threadIdx.x, lane = tid & 63, w = tid >> 6;
  int h = blockIdx.x, kh = h >> 2;
  int qt = 31 - blockIdx.y;
  int qb = qt * 64;
  int m16 = lane & 15, q4 = lane >> 4;
  int wrow0 = qb + w * 16;

  const bhalf* qp = q + (size_t)(wrow0 + m16) * 2048 + h * 64;
  bhalf8 qf0 = *(const bhalf8*)(qp + q4 * 8);
  bhalf8 qf1 = *(const bhalf8*)(qp + 32 + q4 * 8);

  int srow = tid >> 3;
  int scol = ((tid & 7) ^ (srow & 7)) * 8;
  const bhalf* ksrc = k + (size_t)srow * 512 + kh * 64 + scol;
  bhalf* kdst = &Kb[0][0] + w * 512;
  // per-lane V^T base: row (kh*64 + m16), col offset q4*8
  const bhalf* vbase = vt + (size_t)(kh * 64 + m16) * 2048 + q4 * 8;

  auto stage = [&](int c) {
    int buf = c & 1, s0 = c * 64;
#pragma unroll
    for (int j = 0; j < 2; ++j)
      __builtin_amdgcn_global_load_lds((gas_p)(ksrc + (size_t)(s0 + j * 32) * 512),
                                       (las_p)(kdst + buf * 4096 + j * 2048), 16, 0, 0);
  };

  f32x4 zero4 = {0.f, 0.f, 0.f, 0.f};
  f32x4 oac[4];
  float psum = 0.f;
#pragma unroll
  for (int ni = 0; ni < 4; ++ni) oac[ni] = zero4;
  int swz = m16 & 7;
  bhalf* prow = &Pb[w][m16][0];
  int woff = (q4 & 1) << 2;

  stage(0);
  for (int c = 0; c <= qt; ++c) {
    __syncthreads();
    if (c < qt) stage(c + 1);
    int buf = c & 1, s0 = c * 64;
    if (c < qt) {
      // issue V fragment loads early (global, per-wave private; land under QK^T)
      bhalf8 vf[4][2];
#pragma unroll
      for (int ni = 0; ni < 4; ++ni)
#pragma unroll
        for (int ks = 0; ks < 2; ++ks)
          vf[ni][ks] = *(const bhalf8*)(vbase + (size_t)(ni * 16) * 2048 + s0 + ks * 32);
      bhalf8 kf[4][2];
#pragma unroll
      for (int st = 0; st < 4; ++st)
#pragma unroll
        for (int ks = 0; ks < 2; ++ks)
          kf[st][ks] = *(const bhalf8*)&Kb[buf][(st * 16 + m16) * 64 + (((ks * 4 + q4) ^ swz) * 8)];
      f32x4 sv[4];
      __builtin_amdgcn_s_setprio(1);
#pragma unroll
      for (int st = 0; st < 4; ++st) {
        f32x4 t0 = __builtin_amdgcn_mfma_f32_16x16x32_bf16(kf[st][0], qf0, zero4, 0, 0, 0);
        sv[st] = __builtin_amdgcn_mfma_f32_16x16x32_bf16(kf[st][1], qf1, t0, 0, 0, 0);
      }
      __builtin_amdgcn_s_setprio(0);
#pragma unroll
      for (int st = 0; st < 4; ++st) {
        bhalf4 pk;
#pragma unroll
        for (int r = 0; r < 4; ++r) {
          float pe = exp2f(sv[st][r]);
          psum += pe;
          pk[r] = (bhalf)pe;
        }
        *(bhalf4*)(prow + ((((2 * st + (q4 >> 1)) ^ swz) << 3) + woff)) = pk;
      }
      bhalf8 ap0 = *(const bhalf8*)(prow + ((q4 ^ swz) << 3));
      bhalf8 ap1 = *(const bhalf8*)(prow + (((4 + q4) ^ swz) << 3));
      __builtin_amdgcn_s_setprio(1);
#pragma unroll
      for (int ni = 0; ni < 4; ++ni) {
        oac[ni] = __builtin_amdgcn_mfma_f32_16x16x32_bf16(ap0, vf[ni][0], oac[ni], 0, 0, 0);
        oac[ni] = __builtin_amdgcn_mfma_f32_16x16x32_bf16(ap1, vf[ni][1], oac[ni], 0, 0, 0);
      }
      __builtin_amdgcn_s_setprio(0);
    } else {
      int ksmax = (w >= 2) ? 1 : 0;
      bhalf8 vf[4][2];
#pragma unroll
      for (int ni = 0; ni < 4; ++ni)
#pragma unroll
        for (int ks = 0; ks < 2; ++ks)
          if (ks <= ksmax)
            vf[ni][ks] = *(const bhalf8*)(vbase + (size_t)(ni * 16) * 2048 + s0 + ks * 32);
      bhalf8 kf[4][2];
      f32x4 sv[4];
#pragma unroll
      for (int st = 0; st < 4; ++st)
        if (st <= w) {
#pragma unroll
          for (int ks = 0; ks < 2; ++ks)
            kf[st][ks] = *(const bhalf8*)&Kb[buf][(st * 16 + m16) * 64 + (((ks * 4 + q4) ^ swz) * 8)];
          f32x4 t0 = __builtin_amdgcn_mfma_f32_16x16x32_bf16(kf[st][0], qf0, zero4, 0, 0, 0);
          sv[st] = __builtin_amdgcn_mfma_f32_16x16x32_bf16(kf[st][1], qf1, t0, 0, 0, 0);
        }
      int stwr = (w >= 2) ? 3 : 1;
#pragma unroll
      for (int st = 0; st < 4; ++st) {
        if (st > stwr) continue;
        bhalf4 pk;
#pragma unroll
        for (int r = 0; r < 4; ++r) {
          float pe = 0.f;
          if (st < w) {
            pe = exp2f(sv[st][r]);
          } else if (st == w) {
            pe = (q4 * 4 + r <= m16) ? exp2f(sv[st][r]) : 0.f;
          }
          psum += pe;
          pk[r] = (bhalf)pe;
        }
        *(bhalf4*)(prow + ((((2 * st + (q4 >> 1)) ^ swz) << 3) + woff)) = pk;
      }
      bhalf8 ap0 = *(const bhalf8*)(prow + ((q4 ^ swz) << 3));
#pragma unroll
      for (int ni = 0; ni < 4; ++ni)
        oac[ni] = __builtin_amdgcn_mfma_f32_16x16x32_bf16(ap0, vf[ni][0], oac[ni], 0, 0, 0);
      if (ksmax) {
        bhalf8 ap1 = *(const bhalf8*)(prow + (((4 + q4) ^ swz) << 3));
#pragma unroll
        for (int ni = 0; ni < 4; ++ni)
          oac[ni] = __builtin_amdgcn_mfma_f32_16x16x32_bf16(ap1, vf[ni][1], oac[ni], 0, 0, 0);
      }
    }
  }
  psum += __shfl_xor(psum, 16);
  psum += __shfl_xor(psum, 32);
  float inv = 1.0f / psum;
  float invr[4];
#pragma unroll
  for (int r = 0; r < 4; ++r) invr[r] = __shfl(inv, q4 * 4 + r);
#pragma unroll
  for (int ni = 0; ni < 4; ++ni)
#pragma unroll
    for (int r = 0; r < 4; ++r) {
      int trow = wrow0 + q4 * 4 + r;
      o[(size_t)trow * 2048 + h * 64 + ni * 16 + m16] = (bhalf)(oac[ni][r] * invr[r]);
    }
}

extern "C" void kernel_launch(void* const* d_in, const int* in_sizes, int n_in,
                              void* d_out, int out_size, void* d_ws, size_t ws_size,
                              hipStream_t stream) {
  const int* positions = (const int*)d_in[0];
  const float* hidden  = (const float*)d_in[1];
  const float* w_qkv   = (const float*)d_in[2];
  const float* w_out   = (const float*)d_in[3];
  const float* q_ln    = (const float*)d_in[4];
  const float* k_ln    = (const float*)d_in[5];
  float* out = (float*)d_out;

  char* wsp = (char*)d_ws;
  bhalf* hid_bf  = (bhalf*)(wsp);                 //  8,388,608 B
  bhalf* wqkvT   = (bhalf*)(wsp + 8388608);       // 12,582,912 B (3072 x 2048)
  bhalf* woutT   = (bhalf*)(wsp + 20971520);      //  8,388,608 B (2048 x 2048)
  bhalf* q_bf    = (bhalf*)(wsp + 29360128);      //  8,388,608 B
  bhalf* k_bf    = (bhalf*)(wsp + 37748736);      //  2,097,152 B
  bhalf* vt_g    = (bhalf*)(wsp + 41943040);      //  2,097,152 B (written by gemm1)
  bhalf* attn_bf = (bhalf*)(wsp + 44040192);      //  8,388,608 B (ends 52.4 MB)
  // RoPE table (512 KB) aliases the START of attn_bf: consumed by gemm1 BEFORE
  // attn_k writes attn_bf (same stream, sequential) -> no extra workspace.
  float* rope_t  = (float*)(wsp + 44040192);

  prep_k<<<6784, 256, 0, stream>>>(hidden, w_qkv, w_out, positions,
                                   hid_bf, wqkvT, woutT, rope_t);
  gemm1_fused_k<<<384, 256, 0, stream>>>(
      hid_bf, wqkvT, rope_t, q_ln, k_ln, q_bf, k_bf, vt_g);
  attn_k<<<dim3(NQH, 32), 256, 0, stream>>>(q_bf, k_bf, vt_g, attn_bf);
  gemm2_k<<<256, 256, 0, stream>>>(attn_bf, woutT, out);
}

// Round 11
// 207.687 us; speedup vs baseline: 1.2017x; 1.2017x over previous
//
#include <hip/hip_runtime.h>

typedef __bf16 bhalf;
typedef __bf16 bhalf8 __attribute__((ext_vector_type(8)));
typedef __bf16 bhalf4 __attribute__((ext_vector_type(4)));
typedef __bf16 bhalf2 __attribute__((ext_vector_type(2)));
typedef float f32x4 __attribute__((ext_vector_type(4)));

typedef __attribute__((address_space(1))) const void* gas_p;
typedef __attribute__((address_space(3))) void* las_p;

#define T_SEQ 2048
#define HIDN  2048
#define NQH   32
#define NKVH  8
#define DH    64
#define NQKV  3072

// ---------------- fused prep: cast + weight transposes + RoPE table ----------------
__global__ __launch_bounds__(256) void prep_k(const float* __restrict__ hidden,
                                              const float* __restrict__ w_qkv,
                                              const float* __restrict__ w_out,
                                              const int* __restrict__ pos,
                                              bhalf* __restrict__ hid_bf,
                                              bhalf* __restrict__ wqkvT,
                                              bhalf* __restrict__ woutT,
                                              float* __restrict__ rope) {
  __shared__ float tile[64][65];
  int bid = blockIdx.x;
  int tx = threadIdx.x;
  if (bid < 4096) {
    int i = (bid * 256 + tx) * 4;
    float4 v = *(const float4*)(hidden + i);
    bhalf4 o;
    o[0] = (bhalf)v.x; o[1] = (bhalf)v.y; o[2] = (bhalf)v.z; o[3] = (bhalf)v.w;
    *(bhalf4*)(hid_bf + i) = o;
    return;
  }
  if (bid >= 6656) {
    int gid = (bid - 6656) * 256 + tx;   // 32768 = 2048 t x 16 j
    int t = gid >> 4, j = gid & 15;
    float p = (float)pos[t];
    float f0 = exp2f((float)j * -0.6228615177913804f);  // theta^(-j/32)
    float a0 = p * f0, a1 = p * f0 * 0.001f;            // theta^(-16/32) = 1e-3
    float4 cs = {cosf(a0), sinf(a0), cosf(a1), sinf(a1)};
    *(float4*)(rope + (size_t)gid * 4) = cs;
    return;
  }
  const float* in;
  bhalf* out;
  int R, C, bx, by;
  if (bid < 5632) {
    int b2 = bid - 4096;
    in = w_qkv; out = wqkvT; R = HIDN; C = NQKV;
    bx = (b2 % 48) * 64; by = (b2 / 48) * 64;
  } else {
    int b2 = bid - 5632;
    in = w_out; out = woutT; R = HIDN; C = HIDN;
    bx = (b2 % 32) * 64; by = (b2 / 32) * 64;
  }
#pragma unroll
  for (int p = 0; p < 4; ++p) {
    int row = p * 16 + (tx >> 4);
    int col = (tx & 15) * 4;
    float4 v = *(const float4*)(in + (size_t)(by + row) * C + bx + col);
    tile[row][col] = v.x; tile[row][col + 1] = v.y;
    tile[row][col + 2] = v.z; tile[row][col + 3] = v.w;
  }
  __syncthreads();
#pragma unroll
  for (int p = 0; p < 8; ++p) {
    int c = p * 8 + (tx >> 5);
    int rp = tx & 31;
    bhalf2 o2;
    o2[0] = (bhalf)tile[2 * rp][c];
    o2[1] = (bhalf)tile[2 * rp + 1][c];
    *(bhalf2*)(out + (size_t)(bx + c) * R + by + 2 * rp) = o2;
  }
}

#define MFMA_BF16 __builtin_amdgcn_mfma_f32_16x16x32_bf16

// ---- 128(M)x64(N) GEMM core (R1-R3 proven geometry), double-buffered with
// compile-time buffer bases (R7 skeleton). 4 waves stacked in M; wave tile
// 32x64, acc[2][4]. LDS: A dbuf 32KB + B dbuf 16KB = 48KB -> 3 blocks/CU.
#define GEMM64_STAGE(Aps, Bps, k0)                                             \
  _Pragma("unroll")                                                            \
  for (int c = 0; c < 4; ++c)                                                  \
    __builtin_amdgcn_global_load_lds(                                          \
        (gas_p)(asrc_ + (size_t)(c * 32) * 2048 + (k0)),                       \
        (las_p)(Aps + aoff_ + c * 2048), 16, 0, 0);                            \
  _Pragma("unroll")                                                            \
  for (int c = 0; c < 2; ++c)                                                  \
    __builtin_amdgcn_global_load_lds(                                          \
        (gas_p)(bsrc_ + (size_t)(c * 32) * 2048 + (k0)),                       \
        (las_p)(Bps + aoff_ + c * 2048), 16, 0, 0);

#define GEMM64_KS(Aps, Bps, ks)                                                \
  {                                                                            \
    const int co_ = (((ks) * 4 + q4) ^ swz_) * 8;                              \
    bhalf8 af0 = *(const bhalf8*)&Aps[(wm_ +  0 + m16) * 64 + co_];            \
    bhalf8 af1 = *(const bhalf8*)&Aps[(wm_ + 16 + m16) * 64 + co_];            \
    bhalf8 bf0 = *(const bhalf8*)&Bps[( 0 + m16) * 64 + co_];                  \
    bhalf8 bf1 = *(const bhalf8*)&Bps[(16 + m16) * 64 + co_];                  \
    bhalf8 bf2 = *(const bhalf8*)&Bps[(32 + m16) * 64 + co_];                  \
    bhalf8 bf3 = *(const bhalf8*)&Bps[(48 + m16) * 64 + co_];                  \
    acc[0][0] = MFMA_BF16(af0, bf0, acc[0][0], 0, 0, 0);                       \
    acc[0][1] = MFMA_BF16(af0, bf1, acc[0][1], 0, 0, 0);                       \
    acc[0][2] = MFMA_BF16(af0, bf2, acc[0][2], 0, 0, 0);                       \
    acc[0][3] = MFMA_BF16(af0, bf3, acc[0][3], 0, 0, 0);                       \
    acc[1][0] = MFMA_BF16(af1, bf0, acc[1][0], 0, 0, 0);                       \
    acc[1][1] = MFMA_BF16(af1, bf1, acc[1][1], 0, 0, 0);                       \
    acc[1][2] = MFMA_BF16(af1, bf2, acc[1][2], 0, 0, 0);                       \
    acc[1][3] = MFMA_BF16(af1, bf3, acc[1][3], 0, 0, 0);                       \
  }

#define GEMM_CORE_64DB(Aptr, Bptr)                                             \
  {                                                                            \
    const int srow_ = tid >> 3;                                                \
    const int scol_ = ((tid & 7) ^ (srow_ & 7)) * 8;                           \
    const bhalf* asrc_ = (Aptr) + (size_t)(bm + srow_) * 2048 + scol_;         \
    const bhalf* bsrc_ = (Bptr) + (size_t)(bn + srow_) * 2048 + scol_;         \
    const int aoff_ = wv * 512;                                                \
    const int swz_ = m16 & 7;                                                  \
    const int wm_ = wv * 32;                                                   \
    GEMM64_STAGE(As0, Bs0, 0)                                                  \
    for (int k0 = 0; k0 < 2048; k0 += 128) {                                   \
      __syncthreads(); /* buf0 landed; prior buf0 reads done */                \
      GEMM64_STAGE(As1, Bs1, k0 + 64)                                          \
      GEMM64_KS(As0, Bs0, 0)                                                   \
      GEMM64_KS(As0, Bs0, 1)                                                   \
      __syncthreads(); /* buf1 landed; prior buf1 reads done */                \
      if (k0 + 128 < 2048) GEMM64_STAGE(As0, Bs0, k0 + 128)                    \
      GEMM64_KS(As1, Bs1, 0)                                                   \
      GEMM64_KS(As1, Bs1, 1)                                                   \
    }                                                                          \
  }

// ---------------- GEMM1 + fused RMSNorm + RoPE(table) + split + cast + V-transpose --------
// N-tile 64 == one head. grid 768 (= 8 XCDs x 96) -> 3 blocks/CU, 12 waves/CU.
__global__ __launch_bounds__(256, 1) void gemm1_fused_k(const bhalf* __restrict__ A,
                                                        const bhalf* __restrict__ Bt,
                                                        const float* __restrict__ rope,
                                                        const float* __restrict__ qw,
                                                        const float* __restrict__ kw,
                                                        bhalf* __restrict__ qo,
                                                        bhalf* __restrict__ ko,
                                                        bhalf* __restrict__ vt) {
  __shared__ __align__(16) bhalf As0[8192], As1[8192], Bs0[4096], Bs1[4096];
  int tid = threadIdx.x, lane = tid & 63, wv = tid >> 6;
  int m16 = lane & 15, q4 = lane >> 4;
  int orig = blockIdx.x;                      // 768 blocks
  int wgid = (orig & 7) * 96 + (orig >> 3);   // bijective XCD swizzle (768 = 8*96)
  int bx = wgid % 48, by = wgid / 48;
  int bm = by * 128, bn = bx * 64;
  f32x4 zero4 = {0.f, 0.f, 0.f, 0.f};
  f32x4 acc[2][4];
#pragma unroll
  for (int mi = 0; mi < 2; ++mi)
#pragma unroll
    for (int ni = 0; ni < 4; ++ni) acc[mi][ni] = zero4;

  GEMM_CORE_64DB(A, Bt)

  int wr0 = wv * 32;
  int hh = bx;                                // head index
  if (hh < 40) {
    float wd[4];
    const float* wptr = (hh < 32) ? qw : kw;
    float wscale = (hh < 32) ? 0.18033688011112042f : 1.0f;  // 0.125*log2(e) for Q
#pragma unroll
    for (int ni = 0; ni < 4; ++ni) wd[ni] = wptr[ni * 16 + m16] * wscale;
#pragma unroll
    for (int mi = 0; mi < 2; ++mi)
#pragma unroll
      for (int r = 0; r < 4; ++r) {
        int trow = bm + wr0 + mi * 16 + q4 * 4 + r;
        float x0 = acc[mi][0][r], x1 = acc[mi][1][r], x2 = acc[mi][2][r], x3 = acc[mi][3][r];
        float ss = x0 * x0 + x1 * x1 + x2 * x2 + x3 * x3;
        ss += __shfl_xor(ss, 1);
        ss += __shfl_xor(ss, 2);
        ss += __shfl_xor(ss, 4);
        ss += __shfl_xor(ss, 8);
        float sc = rsqrtf(ss * (1.0f / 64.0f) + 1e-5f);
        float y0 = x0 * sc * wd[0], y1 = x1 * sc * wd[1];
        float y2 = x2 * sc * wd[2], y3 = x3 * sc * wd[3];
        float4 cs = *(const float4*)(rope + ((size_t)trow * 16 + m16) * 4);
        float o0 = y0 * cs.x - y2 * cs.y, o2 = y2 * cs.x + y0 * cs.y;
        float o1 = y1 * cs.z - y3 * cs.w, o3 = y3 * cs.z + y1 * cs.w;
        bhalf* dst = (hh < 32) ? (qo + (size_t)trow * 2048 + hh * 64 + m16)
                               : (ko + (size_t)trow * 512 + (hh - 32) * 64 + m16);
        dst[0] = (bhalf)o0; dst[16] = (bhalf)o1; dst[32] = (bhalf)o2; dst[48] = (bhalf)o3;
      }
  } else {
    // V head: write directly transposed -> vt[(hh-40)*64 + d][t], 4 t's per store
#pragma unroll
    for (int mi = 0; mi < 2; ++mi)
#pragma unroll
      for (int ni = 0; ni < 4; ++ni) {
        int trow0 = bm + wr0 + mi * 16 + q4 * 4;
        int d = (hh - 40) * 64 + ni * 16 + m16;
        bhalf4 pk;
        pk[0] = (bhalf)acc[mi][ni][0]; pk[1] = (bhalf)acc[mi][ni][1];
        pk[2] = (bhalf)acc[mi][ni][2]; pk[3] = (bhalf)acc[mi][ni][3];
        *(bhalf4*)(vt + (size_t)d * 2048 + trow0) = pk;
      }
  }
}

// ---------------- GEMM2: plain fp32-out epilogue ----------------
// grid 512 (= 8 XCDs x 64) -> 2 blocks/CU, 8 waves/CU.
__global__ __launch_bounds__(256, 1) void gemm2_k(const bhalf* __restrict__ A,
                                                  const bhalf* __restrict__ Bt,
                                                  float* __restrict__ C) {
  __shared__ __align__(16) bhalf As0[8192], As1[8192], Bs0[4096], Bs1[4096];
  int tid = threadIdx.x, lane = tid & 63, wv = tid >> 6;
  int m16 = lane & 15, q4 = lane >> 4;
  int orig = blockIdx.x;                      // 512 blocks
  int wgid = (orig & 7) * 64 + (orig >> 3);   // bijective XCD swizzle (512 = 8*64)
  int bx = wgid & 31, by = wgid >> 5;
  int bm = by * 128, bn = bx * 64;
  f32x4 zero4 = {0.f, 0.f, 0.f, 0.f};
  f32x4 acc[2][4];
#pragma unroll
  for (int mi = 0; mi < 2; ++mi)
#pragma unroll
    for (int ni = 0; ni < 4; ++ni) acc[mi][ni] = zero4;

  GEMM_CORE_64DB(A, Bt)

  int wr0 = wv * 32;
#pragma unroll
  for (int mi = 0; mi < 2; ++mi)
#pragma unroll
    for (int r = 0; r < 4; ++r) {
      size_t base = (size_t)(bm + wr0 + mi * 16 + q4 * 4 + r) * 2048 + bn + m16;
      C[base] = acc[mi][0][r]; C[base + 16] = acc[mi][1][r];
      C[base + 32] = acc[mi][2][r]; C[base + 48] = acc[mi][3][r];
    }
}

// ---------------- flash attention (causal GQA), fixed-max softmax ----------------
// EXACT R7 version (measured 49.4 us): grid (NQH,32), 1024 blocks, 4/CU;
// K AND V LDS-staged double-buffered via global_load_lds; swapped QK^T,
// packed P writes, bare-exp2 softmax. Frozen — R8 (balance) and R9 (V-direct)
// both regressed; this structure's TLP-based latency hiding is the optimum.
__global__ __launch_bounds__(256) void attn_k(const bhalf* __restrict__ q,
                                              const bhalf* __restrict__ k,
                                              const bhalf* __restrict__ vt,
                                              bhalf* __restrict__ o) {
  __shared__ __align__(16) bhalf Kb[2][4096];
  __shared__ __align__(16) bhalf Vb[2][4096];
  __shared__ __align__(16) bhalf Pb[4][16][64];
  int tid = threadIdx.x, lane = tid & 63, w = tid >> 6;
  int h = blockIdx.x, kh = h >> 2;
  int qt = 31 - blockIdx.y;
  int qb = qt * 64;
  int m16 = lane & 15, q4 = lane >> 4;
  int wrow0 = qb + w * 16;

  const bhalf* qp = q + (size_t)(wrow0 + m16) * 2048 + h * 64;
  bhalf8 qf0 = *(const bhalf8*)(qp + q4 * 8);
  bhalf8 qf1 = *(const bhalf8*)(qp + 32 + q4 * 8);

  int srow = tid >> 3;
  int scol = ((tid & 7) ^ (srow & 7)) * 8;
  const bhalf* ksrc = k + (size_t)srow * 512 + kh * 64 + scol;
  const bhalf* vsrc = vt + (size_t)(kh * 64 + srow) * 2048 + scol;
  bhalf* kdst = &Kb[0][0] + w * 512;
  bhalf* vdst = &Vb[0][0] + w * 512;

  auto stage = [&](int c) {
    int buf = c & 1, s0 = c * 64;
#pragma unroll
    for (int j = 0; j < 2; ++j) {
      __builtin_amdgcn_global_load_lds((gas_p)(ksrc + (size_t)(s0 + j * 32) * 512),
                                       (las_p)(kdst + buf * 4096 + j * 2048), 16, 0, 0);
      __builtin_amdgcn_global_load_lds((gas_p)(vsrc + (size_t)(j * 32) * 2048 + s0),
                                       (las_p)(vdst + buf * 4096 + j * 2048), 16, 0, 0);
    }
  };

  f32x4 zero4 = {0.f, 0.f, 0.f, 0.f};
  f32x4 oac[4];
  float psum = 0.f;
#pragma unroll
  for (int ni = 0; ni < 4; ++ni) oac[ni] = zero4;
  int swz = m16 & 7;
  bhalf* prow = &Pb[w][m16][0];
  int woff = (q4 & 1) << 2;

  stage(0);
  for (int c = 0; c <= qt; ++c) {
    __syncthreads();
    if (c < qt) stage(c + 1);
    int buf = c & 1;
    if (c < qt) {
      bhalf8 kf[4][2];
#pragma unroll
      for (int st = 0; st < 4; ++st)
#pragma unroll
        for (int ks = 0; ks < 2; ++ks)
          kf[st][ks] = *(const bhalf8*)&Kb[buf][(st * 16 + m16) * 64 + (((ks * 4 + q4) ^ swz) * 8)];
      f32x4 sv[4];
      __builtin_amdgcn_s_setprio(1);
#pragma unroll
      for (int st = 0; st < 4; ++st) {
        f32x4 t0 = __builtin_amdgcn_mfma_f32_16x16x32_bf16(kf[st][0], qf0, zero4, 0, 0, 0);
        sv[st] = __builtin_amdgcn_mfma_f32_16x16x32_bf16(kf[st][1], qf1, t0, 0, 0, 0);
      }
      __builtin_amdgcn_s_setprio(0);
#pragma unroll
      for (int st = 0; st < 4; ++st) {
        bhalf4 pk;
#pragma unroll
        for (int r = 0; r < 4; ++r) {
          float pe = exp2f(sv[st][r]);
          psum += pe;
          pk[r] = (bhalf)pe;
        }
        *(bhalf4*)(prow + ((((2 * st + (q4 >> 1)) ^ swz) << 3) + woff)) = pk;
      }
      bhalf8 vf[4][2];
#pragma unroll
      for (int ni = 0; ni < 4; ++ni)
#pragma unroll
        for (int ks = 0; ks < 2; ++ks)
          vf[ni][ks] = *(const bhalf8*)&Vb[buf][(ni * 16 + m16) * 64 + (((ks * 4 + q4) ^ swz) * 8)];
      bhalf8 ap0 = *(const bhalf8*)(prow + ((q4 ^ swz) << 3));
      bhalf8 ap1 = *(const bhalf8*)(prow + (((4 + q4) ^ swz) << 3));
      __builtin_amdgcn_s_setprio(1);
#pragma unroll
      for (int ni = 0; ni < 4; ++ni) {
        oac[ni] = __builtin_amdgcn_mfma_f32_16x16x32_bf16(ap0, vf[ni][0], oac[ni], 0, 0, 0);
        oac[ni] = __builtin_amdgcn_mfma_f32_16x16x32_bf16(ap1, vf[ni][1], oac[ni], 0, 0, 0);
      }
      __builtin_amdgcn_s_setprio(0);
    } else {
      bhalf8 kf[4][2];
      f32x4 sv[4];
#pragma unroll
      for (int st = 0; st < 4; ++st)
        if (st <= w) {
#pragma unroll
          for (int ks = 0; ks < 2; ++ks)
            kf[st][ks] = *(const bhalf8*)&Kb[buf][(st * 16 + m16) * 64 + (((ks * 4 + q4) ^ swz) * 8)];
          f32x4 t0 = __builtin_amdgcn_mfma_f32_16x16x32_bf16(kf[st][0], qf0, zero4, 0, 0, 0);
          sv[st] = __builtin_amdgcn_mfma_f32_16x16x32_bf16(kf[st][1], qf1, t0, 0, 0, 0);
        }
      int stwr = (w >= 2) ? 3 : 1;
#pragma unroll
      for (int st = 0; st < 4; ++st) {
        if (st > stwr) continue;
        bhalf4 pk;
#pragma unroll
        for (int r = 0; r < 4; ++r) {
          float pe = 0.f;
          if (st < w) {
            pe = exp2f(sv[st][r]);
          } else if (st == w) {
            pe = (q4 * 4 + r <= m16) ? exp2f(sv[st][r]) : 0.f;
          }
          psum += pe;
          pk[r] = (bhalf)pe;
        }
        *(bhalf4*)(prow + ((((2 * st + (q4 >> 1)) ^ swz) << 3) + woff)) = pk;
      }
      int ksmax = (w >= 2) ? 1 : 0;
      bhalf8 vf[4][2];
#pragma unroll
      for (int ni = 0; ni < 4; ++ni)
#pragma unroll
        for (int ks = 0; ks < 2; ++ks)
          if (ks <= ksmax)
            vf[ni][ks] = *(const bhalf8*)&Vb[buf][(ni * 16 + m16) * 64 + (((ks * 4 + q4) ^ swz) * 8)];
      bhalf8 ap0 = *(const bhalf8*)(prow + ((q4 ^ swz) << 3));
#pragma unroll
      for (int ni = 0; ni < 4; ++ni)
        oac[ni] = __builtin_amdgcn_mfma_f32_16x16x32_bf16(ap0, vf[ni][0], oac[ni], 0, 0, 0);
      if (ksmax) {
        bhalf8 ap1 = *(const bhalf8*)(prow + (((4 + q4) ^ swz) << 3));
#pragma unroll
        for (int ni = 0; ni < 4; ++ni)
          oac[ni] = __builtin_amdgcn_mfma_f32_16x16x32_bf16(ap1, vf[ni][1], oac[ni], 0, 0, 0);
      }
    }
  }
  psum += __shfl_xor(psum, 16);
  psum += __shfl_xor(psum, 32);
  float inv = 1.0f / psum;
  float invr[4];
#pragma unroll
  for (int r = 0; r < 4; ++r) invr[r] = __shfl(inv, q4 * 4 + r);
#pragma unroll
  for (int ni = 0; ni < 4; ++ni)
#pragma unroll
    for (int r = 0; r < 4; ++r) {
      int trow = wrow0 + q4 * 4 + r;
      o[(size_t)trow * 2048 + h * 64 + ni * 16 + m16] = (bhalf)(oac[ni][r] * invr[r]);
    }
}

extern "C" void kernel_launch(void* const* d_in, const int* in_sizes, int n_in,
                              void* d_out, int out_size, void* d_ws, size_t ws_size,
                              hipStream_t stream) {
  const int* positions = (const int*)d_in[0];
  const float* hidden  = (const float*)d_in[1];
  const float* w_qkv   = (const float*)d_in[2];
  const float* w_out   = (const float*)d_in[3];
  const float* q_ln    = (const float*)d_in[4];
  const float* k_ln    = (const float*)d_in[5];
  float* out = (float*)d_out;

  char* wsp = (char*)d_ws;
  bhalf* hid_bf  = (bhalf*)(wsp);                 //  8,388,608 B
  bhalf* wqkvT   = (bhalf*)(wsp + 8388608);       // 12,582,912 B (3072 x 2048)
  bhalf* woutT   = (bhalf*)(wsp + 20971520);      //  8,388,608 B (2048 x 2048)
  bhalf* q_bf    = (bhalf*)(wsp + 29360128);      //  8,388,608 B
  bhalf* k_bf    = (bhalf*)(wsp + 37748736);      //  2,097,152 B
  bhalf* vt_g    = (bhalf*)(wsp + 41943040);      //  2,097,152 B (written by gemm1)
  bhalf* attn_bf = (bhalf*)(wsp + 44040192);      //  8,388,608 B (ends 52.4 MB)
  // RoPE table (512 KB) aliases the START of attn_bf: consumed by gemm1 BEFORE
  // attn_k writes attn_bf (same stream, sequential) -> no extra workspace.
  float* rope_t  = (float*)(wsp + 44040192);

  prep_k<<<6784, 256, 0, stream>>>(hidden, w_qkv, w_out, positions,
                                   hid_bf, wqkvT, woutT, rope_t);
  gemm1_fused_k<<<768, 256, 0, stream>>>(
      hid_bf, wqkvT, rope_t, q_ln, k_ln, q_bf, k_bf, vt_g);
  attn_k<<<dim3(NQH, 32), 256, 0, stream>>>(q_bf, k_bf, vt_g, attn_bf);
  gemm2_k<<<512, 256, 0, stream>>>(attn_bf, woutT, out);
}